// Round 1
// baseline (46.948 us; speedup 1.0000x reference)
//
#include <hip/hip_runtime.h>
#include <math.h>

// SpectralContrastPrior: per (b, band, t) column, mean of top-3 and bottom-3
// over the band's frequency rows (170 for bands 0..4, 175 for band 5).
// Input:  power_spec (32, 1025, 2000) f32
// Output: peaks (32, 6, 2000) f32 followed by valleys (32, 6, 2000) f32, flat.

constexpr int B_   = 32;
constexpr int NF   = 1025;
constexpr int T_   = 2000;
constexpr int NB   = 6;
constexpr int BAND = NF / NB;   // 170
constexpr int VEC  = 2;         // float2 per thread along t
constexpr int TG   = T_ / VEC;  // 1000

// Maintain sorted top-3 (t0 >= t1 >= t2): 5 min/max ops.
__device__ __forceinline__ void ins_top(float& t0, float& t1, float& t2, float x) {
    float lo0 = fminf(t0, x);
    t0 = fmaxf(t0, x);
    float lo1 = fminf(t1, lo0);
    t1 = fmaxf(t1, lo0);
    t2 = fmaxf(t2, lo1);
}
// Maintain sorted bottom-3 (b0 <= b1 <= b2): 5 min/max ops.
__device__ __forceinline__ void ins_bot(float& b0, float& b1, float& b2, float x) {
    float hi0 = fmaxf(b0, x);
    b0 = fminf(b0, x);
    float hi1 = fmaxf(b1, hi0);
    b1 = fminf(b1, hi0);
    b2 = fminf(b2, hi1);
}

__global__ __launch_bounds__(256) void scp_kernel(const float* __restrict__ in,
                                                  float* __restrict__ out) {
    int idx = blockIdx.x * blockDim.x + threadIdx.x;
    if (idx >= B_ * NB * TG) return;

    int tg   = idx % TG;          // consecutive lanes -> consecutive t: coalesced
    int rest = idx / TG;
    int band = rest % NB;
    int b    = rest / NB;

    int row0  = band * BAND;
    int nrows = (band == NB - 1) ? (NF - row0) : BAND;   // 175 or 170

    const float* p = in + (size_t)b * NF * T_ + (size_t)row0 * T_ + (size_t)tg * VEC;

    // Two t-columns per thread (x / y of the float2).
    float ax0 = -INFINITY, ax1 = -INFINITY, ax2 = -INFINITY;
    float an0 =  INFINITY, an1 =  INFINITY, an2 =  INFINITY;
    float bx0 = -INFINITY, bx1 = -INFINITY, bx2 = -INFINITY;
    float bn0 =  INFINITY, bn1 =  INFINITY, bn2 =  INFINITY;

    #pragma unroll 5   // 170 % 5 == 0 and 175 % 5 == 0
    for (int r = 0; r < nrows; ++r) {
        float2 v = *reinterpret_cast<const float2*>(p + (size_t)r * T_);
        ins_top(ax0, ax1, ax2, v.x);
        ins_bot(an0, an1, an2, v.x);
        ins_top(bx0, bx1, bx2, v.y);
        ins_bot(bn0, bn1, bn2, v.y);
    }

    const float inv3 = 1.0f / 3.0f;
    size_t o    = (size_t)b * NB * T_ + (size_t)band * T_ + (size_t)tg * VEC;
    size_t voff = (size_t)B_ * NB * T_;

    float2 pk = make_float2((ax0 + ax1 + ax2) * inv3, (bx0 + bx1 + bx2) * inv3);
    float2 vl = make_float2((an0 + an1 + an2) * inv3, (bn0 + bn1 + bn2) * inv3);
    *reinterpret_cast<float2*>(out + o)        = pk;   // peaks
    *reinterpret_cast<float2*>(out + voff + o) = vl;   // valleys
}

extern "C" void kernel_launch(void* const* d_in, const int* in_sizes, int n_in,
                              void* d_out, int out_size, void* d_ws, size_t ws_size,
                              hipStream_t stream) {
    const float* in = (const float*)d_in[0];
    float* out = (float*)d_out;

    int total = B_ * NB * TG;                 // 192000 threads
    int block = 256;
    int grid  = (total + block - 1) / block;  // 750 blocks
    scp_kernel<<<grid, block, 0, stream>>>(in, out);
}